// Round 1
// 428.018 us; speedup vs baseline: 1.1034x; 1.1034x over previous
//
#include <hip/hip_runtime.h>
#include <hip/hip_bf16.h>
#include <math.h>

#define EMB 1024
#define HEADS 16
#define HEAD_DIM 64
#define FF_DIM 4096
#define SEQ 2048
#define BATCH 2
#define NTOK (BATCH * SEQ)   // 4096 rows
#define LN_EPS 1e-5f
#define QKV_N 3072
// fold softmax scale into q: 0.125 * log2(e)
#define Q_PRESCALE 0.18033688011112042f

typedef __attribute__((ext_vector_type(8))) short s8v;   // 8 bf16 (4 VGPRs)
typedef __attribute__((ext_vector_type(4))) float f4v;   // MFMA accumulator

__device__ __forceinline__ unsigned short f2bf(float f) {
    union { __hip_bfloat16 h; unsigned short u; } cv;
    cv.h = __float2bfloat16(f);
    return cv.u;
}

__device__ __forceinline__ float fast_exp2(float x) {
#if __has_builtin(__builtin_amdgcn_exp2f)
    return __builtin_amdgcn_exp2f(x);
#else
    return exp2f(x);
#endif
}

__device__ __forceinline__ float gelu_f(float x) {
    const float c = 0.7978845608028654f;  // sqrt(2/pi)
    float x3 = x * x * x;
    return 0.5f * x * (1.0f + tanhf(c * (x + 0.044715f * x3)));
}

#define GLDS(gp, lp)                                                        \
    __builtin_amdgcn_global_load_lds(                                       \
        (const __attribute__((address_space(1))) void*)(gp),                \
        (__attribute__((address_space(3))) void*)(lp), 16, 0, 0)

// sync helpers for the 8-phase schedule (raw barrier: no compiler vmcnt(0) drain)
#define BAR()   do { __builtin_amdgcn_s_barrier(); __builtin_amdgcn_sched_barrier(0); } while (0)
#define LGKM0() do { asm volatile("s_waitcnt lgkmcnt(0)" ::: "memory"); __builtin_amdgcn_sched_barrier(0); } while (0)
#define VMC4()  do { asm volatile("s_waitcnt vmcnt(4)" ::: "memory"); __builtin_amdgcn_sched_barrier(0); } while (0)
#define VMC0()  do { asm volatile("s_waitcnt vmcnt(0)" ::: "memory"); __builtin_amdgcn_sched_barrier(0); } while (0)

// ---------------- LayerNorm -> bf16 out ----------------------------------------------
__global__ __launch_bounds__(256) void ln_bf16_kernel(const float* __restrict__ x,
                                                      const float* __restrict__ scale,
                                                      const float* __restrict__ shift,
                                                      unsigned short* __restrict__ out) {
    int row = blockIdx.x;
    int tid = threadIdx.x;
    const float4 xv = ((const float4*)(x + (size_t)row * EMB))[tid];
    float s  = xv.x + xv.y + xv.z + xv.w;
    float ss = xv.x * xv.x + xv.y * xv.y + xv.z * xv.z + xv.w * xv.w;
    __shared__ float2 red[256];
    red[tid] = make_float2(s, ss);
    __syncthreads();
    for (int off = 128; off > 0; off >>= 1) {
        if (tid < off) {
            red[tid].x += red[tid + off].x;
            red[tid].y += red[tid + off].y;
        }
        __syncthreads();
    }
    float mean = red[0].x * (1.0f / EMB);
    float var  = red[0].y * (1.0f / EMB) - mean * mean;
    float rstd = rsqrtf(var + LN_EPS);
    float4 sc4 = ((const float4*)scale)[tid];
    float4 sh4 = ((const float4*)shift)[tid];
    ushort4 o;
    o.x = f2bf(sc4.x * (xv.x - mean) * rstd + sh4.x);
    o.y = f2bf(sc4.y * (xv.y - mean) * rstd + sh4.y);
    o.z = f2bf(sc4.z * (xv.z - mean) * rstd + sh4.z);
    o.w = f2bf(sc4.w * (xv.w - mean) * rstd + sh4.w);
    *(ushort4*)(out + (size_t)row * EMB + tid * 4) = o;
}

// ---------------- fused fp32 [K][N] -> bf16 [N][K] transpose-convert (ALL weights) ----
__device__ __forceinline__ void tconv_tile(const float* __restrict__ W,
                                           unsigned short* __restrict__ Wt,
                                           int K, int N, int bx, int by, int tid) {
    __shared__ float t[64][65];
    int n0 = bx * 64, k0 = by * 64;
#pragma unroll
    for (int it = 0; it < 4; ++it) {
        int f = tid + it * 256;
        int r = f >> 4, c = (f & 15) * 4;
        float4 w = *(const float4*)(W + (size_t)(k0 + r) * N + n0 + c);
        t[r][c] = w.x; t[r][c + 1] = w.y; t[r][c + 2] = w.z; t[r][c + 3] = w.w;
    }
    __syncthreads();
#pragma unroll
    for (int it = 0; it < 4; ++it) {
        int f = tid + it * 256;
        int rn = f >> 4, ck = (f & 15) * 4;
        ushort4 o;
        o.x = f2bf(t[ck + 0][rn]);
        o.y = f2bf(t[ck + 1][rn]);
        o.z = f2bf(t[ck + 2][rn]);
        o.w = f2bf(t[ck + 3][rn]);
        *(ushort4*)(Wt + (size_t)(n0 + rn) * K + k0 + ck) = o;
    }
}

__global__ __launch_bounds__(256) void tconv_all_kernel(
    const float* __restrict__ Wq, const float* __restrict__ Wk,
    const float* __restrict__ Wv, const float* __restrict__ Wo,
    const float* __restrict__ W1, const float* __restrict__ W2,
    unsigned short* __restrict__ Wqkv_t, unsigned short* __restrict__ Wo_t,
    unsigned short* __restrict__ W1_t, unsigned short* __restrict__ W2_t) {
    int b = blockIdx.x;
    int tid = threadIdx.x;
    if (b < 256)        tconv_tile(Wq, Wqkv_t,                      EMB, EMB,    b & 15, b >> 4, tid);
    else if (b < 512)   tconv_tile(Wk, Wqkv_t + (size_t)1024 * EMB, EMB, EMB,    (b - 256) & 15, (b - 256) >> 4, tid);
    else if (b < 768)   tconv_tile(Wv, Wqkv_t + (size_t)2048 * EMB, EMB, EMB,    (b - 512) & 15, (b - 512) >> 4, tid);
    else if (b < 1024)  tconv_tile(Wo, Wo_t,                        EMB, EMB,    (b - 768) & 15, (b - 768) >> 4, tid);
    else if (b < 2048)  tconv_tile(W1, W1_t,                        EMB, FF_DIM, (b - 1024) & 63, (b - 1024) >> 6, tid);
    else                tconv_tile(W2, W2_t,                        FF_DIM, EMB, (b - 2048) & 15, (b - 2048) >> 4, tid);
}

// ---------------- split-K reduce: out = p0 + p1 + bias + residual ---------------------
__global__ __launch_bounds__(256) void reduce_kernel(const float* __restrict__ p0,
                                                     const float* __restrict__ p1,
                                                     const float* __restrict__ bias,
                                                     const float* __restrict__ residual,
                                                     float* __restrict__ out) {
    size_t i4 = ((size_t)blockIdx.x * 256 + threadIdx.x) * 4;
    float4 a = *(const float4*)(p0 + i4);
    float4 b = *(const float4*)(p1 + i4);
    float4 r = *(const float4*)(residual + i4);
    int col = (int)(i4 & (EMB - 1));
    float4 bs = *(const float4*)(bias + col);
    float4 o;
    o.x = a.x + b.x + r.x + bs.x;
    o.y = a.y + b.y + r.y + bs.y;
    o.z = a.z + b.z + r.z + bs.z;
    o.w = a.w + b.w + r.w + bs.w;
    *(float4*)(out + i4) = o;
}

// ---------------- fused split-K reduce + LayerNorm ------------------------------------
__global__ __launch_bounds__(256) void reduce_ln_kernel(const float* __restrict__ p0,
                                                        const float* __restrict__ p1,
                                                        const float* __restrict__ bias,
                                                        const float* __restrict__ residual,
                                                        float* __restrict__ x1,
                                                        const float* __restrict__ scale,
                                                        const float* __restrict__ shift,
                                                        unsigned short* __restrict__ out) {
    int row = blockIdx.x;
    int tid = threadIdx.x;
    size_t i4 = (size_t)row * EMB + tid * 4;
    float4 a = *(const float4*)(p0 + i4);
    float4 b = *(const float4*)(p1 + i4);
    float4 r = *(const float4*)(residual + i4);
    float4 bs = *(const float4*)(bias + tid * 4);
    float4 xv;
    xv.x = a.x + b.x + r.x + bs.x;
    xv.y = a.y + b.y + r.y + bs.y;
    xv.z = a.z + b.z + r.z + bs.z;
    xv.w = a.w + b.w + r.w + bs.w;
    *(float4*)(x1 + i4) = xv;

    float s  = xv.x + xv.y + xv.z + xv.w;
    float ss = xv.x * xv.x + xv.y * xv.y + xv.z * xv.z + xv.w * xv.w;
    __shared__ float2 red[256];
    red[tid] = make_float2(s, ss);
    __syncthreads();
    for (int off = 128; off > 0; off >>= 1) {
        if (tid < off) {
            red[tid].x += red[tid + off].x;
            red[tid].y += red[tid + off].y;
        }
        __syncthreads();
    }
    float mean = red[0].x * (1.0f / EMB);
    float var  = red[0].y * (1.0f / EMB) - mean * mean;
    float rstd = rsqrtf(var + LN_EPS);
    float4 sc4 = ((const float4*)scale)[tid];
    float4 sh4 = ((const float4*)shift)[tid];
    ushort4 o;
    o.x = f2bf(sc4.x * (xv.x - mean) * rstd + sh4.x);
    o.y = f2bf(sc4.y * (xv.y - mean) * rstd + sh4.y);
    o.z = f2bf(sc4.z * (xv.z - mean) * rstd + sh4.z);
    o.w = f2bf(sc4.w * (xv.w - mean) * rstd + sh4.w);
    *(ushort4*)(out + i4) = o;
}

// ================= 8-phase 256x256 bf16 MFMA GEMM (HK schedule, plain HIP) ============
// BM=BN=256, BK=64, 512 threads = 8 waves (2M x 4N), per-wave output 128x64.
// LDS 128 KiB: A/B each [2 buf][2 half][8 kc][128 row][8 shorts] (k-chunk-blocked:
// conflict-free ds_read_b128 AND linear global_load_lds dest -- no XOR swizzle needed).
// Counted vmcnt(4) at phases 4/8 only; raw s_barrier (no vmcnt(0) drain in main loop);
// setprio(1) around each 16-MFMA cluster.
// Stage-slot schedule (iteration i computes tiles T0=2i (buf0), T1=2i+1 (buf1)):
//   P1: A0(T1)  P2: A1(T1)  P3: B0(T0+2)  P4: B1(T0+2) +vmcnt(4)
//   P5: A0(T0+2) P6: A1(T0+2) P7: B0(T1+2) P8: B1(T1+2) +vmcnt(4)
// Each stage lands only after the barrier following its buffer-half's last reader.
__global__ __launch_bounds__(512, 2) void gemm_8ph_kernel(
    const unsigned short* __restrict__ A,   // [M,K] bf16
    const unsigned short* __restrict__ Bt,  // [N,K] bf16
    unsigned short* __restrict__ Cb,        // bf16 out
    int M, int N, int K,
    const float* __restrict__ bias,
    int do_gelu, int qkv_mode,
    unsigned short* __restrict__ vt)
{
    __shared__ short lds[65536];   // 128 KiB: A at [0,64K), B at [64K,128K) bytes

    int tid = threadIdx.x;
    int w = tid >> 6, lane = tid & 63;
    int wr = w >> 2, wc = w & 3;          // wave rows wr*128.., cols wc*64..
    int quad = lane >> 4, ln = lane & 15;

    // XCD-bijective block swizzle (nwg % 8 == 0 for both call sites)
    int nbx = N >> 8;
    int nwg = (M >> 8) * nbx;
    int bid = (int)blockIdx.x;
    int swz = (nwg & 7) ? bid : ((bid & 7) * (nwg >> 3) + (bid >> 3));
    int by = swz / nbx, bx = swz - by * nbx;
    int m0 = by << 8, n0 = bx << 8;

    f4v acc[8][4];
#pragma unroll
    for (int i = 0; i < 8; ++i)
#pragma unroll
        for (int j = 0; j < 4; ++j) { f4v z = {0.f, 0.f, 0.f, 0.f}; acc[i][j] = z; }

    size_t Kby = (size_t)K << 1;
    size_t AhS = (size_t)128 * Kby;       // half-tile row-block stride (A and B)
    const char* AgC = (const char*)A + (size_t)(m0 + (tid & 127)) * Kby + (size_t)((tid >> 7) << 4);
    const char* BgC = (const char*)Bt + (size_t)(n0 + (tid & 127)) * Kby + (size_t)((tid >> 7) << 4);
    char* ldsC = (char*)lds;
    int tid16 = tid << 4;

    // frag read bases (shorts): A[buf][half=wr][kc=ks*4+quad][row=f*16+ln][8]
    const short* aRd = lds + wr * 8192 + quad * 1024 + ln * 8;
    const short* bRd = lds + 32768 + (wc >> 1) * 8192 + (wc & 1) * 512 + quad * 1024 + ln * 8;

#define STG_A(tb, h, b) do {                                                     \
    const char* s_ = AgC + (size_t)(h) * AhS + (size_t)(tb);                     \
    char* d_ = ldsC + (b) * 32768 + (h) * 16384 + tid16;                         \
    GLDS(s_, d_); GLDS(s_ + 64, d_ + 8192); } while (0)
#define STG_B(tb, h, b) do {                                                     \
    const char* s_ = BgC + (size_t)(h) * AhS + (size_t)(tb);                     \
    char* d_ = ldsC + 65536 + (b) * 32768 + (h) * 16384 + tid16;                 \
    GLDS(s_, d_); GLDS(s_ + 64, d_ + 8192); } while (0)
#define RD_A4(mg, b) do {                                                        \
    _Pragma("unroll") for (int f_ = 0; f_ < 4; ++f_) {                           \
        af[f_][0] = *(const s8v*)(aRd + (b) * 16384 + ((mg) * 4 + f_) * 128);    \
        af[f_][1] = *(const s8v*)(aRd + (b) * 16384 + 4096 + ((mg) * 4 + f_) * 128); } } while (0)
#define RD_B2(dst, ng, b) do {                                                   \
    _Pragma("unroll") for (int g_ = 0; g_ < 2; ++g_) {                           \
        dst[g_][0] = *(const s8v*)(bRd + (b) * 16384 + ((ng) * 2 + g_) * 128);   \
        dst[g_][1] = *(const s8v*)(bRd + (b) * 16384 + 4096 + ((ng) * 2 + g_) * 128); } } while (0)
#define MF_Q(mg, bsrc, ng) do {                                                  \
    __builtin_amdgcn_s_setprio(1);                                               \
    _Pragma("unroll") for (int f_ = 0; f_ < 4; ++f_)                             \
    _Pragma("unroll") for (int g_ = 0; g_ < 2; ++g_)                             \
    _Pragma("unroll") for (int k_ = 0; k_ < 2; ++k_)                             \
        acc[(mg) * 4 + f_][(ng) * 2 + g_] = __builtin_amdgcn_mfma_f32_16x16x32_bf16( \
            af[f_][k_], bsrc[g_][k_], acc[(mg) * 4 + f_][(ng) * 2 + g_], 0, 0, 0); \
    __builtin_amdgcn_s_setprio(0); } while (0)

    s8v af[4][2], bf0[2][2], bf1[2][2];

    // prologue: tile0 fully + tile1 B-halves (12 loads); wait keeps tile1 B in flight
    STG_A(0, 0, 0); STG_A(0, 1, 0);
    STG_B(0, 0, 0); STG_B(0, 1, 0);
    STG_B(128, 0, 1); STG_B(128, 1, 1);
    VMC4();
    BAR();

    int nIter = K >> 7;   // K multiple of 128
    for (int it = 0; it < nIter; ++it) {
        size_t base = (size_t)it << 8;    // tile 2it byte offset in K
        bool pf = (it + 1 < nIter);

        // ---- K-tile T0 = 2it (buf0) ----
        // P1: quadrant (m0,n0)
        RD_A4(0, 0); RD_B2(bf0, 0, 0);
        STG_A(base + 128, 0, 1);
        BAR(); LGKM0();
        MF_Q(0, bf0, 0);
        BAR();
        // P2: (m0,n1)
        RD_B2(bf1, 1, 0);
        STG_A(base + 128, 1, 1);
        BAR(); LGKM0();
        MF_Q(0, bf1, 1);
        BAR();
        // P3: (m1,n0)
        RD_A4(1, 0);
        if (pf) STG_B(base + 256, 0, 0);
        BAR(); LGKM0();
        MF_Q(1, bf0, 0);
        BAR();
        // P4: (m1,n1); counted wait covers tile T1 for P5..P8
        if (pf) STG_B(base + 256, 1, 0);
        BAR();
        MF_Q(1, bf1, 1);
        if (pf) { VMC4(); } else { VMC0(); }
        BAR();

        // ---- K-tile T1 = 2it+1 (buf1) ----
        // P5
        RD_A4(0, 1); RD_B2(bf0, 0, 1);
        if (pf) STG_A(base + 256, 0, 0);
        BAR(); LGKM0();
        MF_Q(0, bf0, 0);
        BAR();
        // P6
        RD_B2(bf1, 1, 1);
        if (pf) STG_A(base + 256, 1, 0);
        BAR(); LGKM0();
        MF_Q(0, bf1, 1);
        BAR();
        // P7
        RD_A4(1, 1);
        if (pf) STG_B(base + 384, 0, 1);
        BAR(); LGKM0();
        MF_Q(1, bf0, 0);
        BAR();
        // P8: counted wait covers tile T0+2 for next iteration's P1..P4
        if (pf) STG_B(base + 384, 1, 1);
        BAR();
        MF_Q(1, bf1, 1);
        if (pf) VMC4();
        BAR();
    }
#undef STG_A
#undef STG_B
#undef RD_A4
#undef RD_B2
#undef MF_Q

    // epilogue: C/D layout col=lane&15, row=(lane>>4)*4+reg
    int cn  = n0 + wc * 64 + ln;
    int cm0 = m0 + wr * 128 + quad * 4;

    if (qkv_mode) {
        if (n0 < 2048) {
            float sc = (n0 < 1024) ? Q_PRESCALE : 1.0f;
#pragma unroll
            for (int g = 0; g < 4; ++g) {
                int gn = cn + g * 16;
#pragma unroll
                for (int f = 0; f < 8; ++f)
#pragma unroll
                    for (int r = 0; r < 4; ++r)
                        Cb[(size_t)(cm0 + f * 16 + r) * 2048 + gn] = f2bf(acc[f][g][r] * sc);
            }
        } else {
#pragma unroll
            for (int g = 0; g < 4; ++g) {
                int gn = cn + g * 16 - 2048;       // h*64+d in [0,1024)
#pragma unroll
                for (int f = 0; f < 8; ++f) {
                    int gm0 = cm0 + f * 16;
                    int bb = gm0 >> 11, s0 = gm0 & 2047;
                    ushort4 pk;
                    pk.x = f2bf(acc[f][g][0]);
                    pk.y = f2bf(acc[f][g][1]);
                    pk.z = f2bf(acc[f][g][2]);
                    pk.w = f2bf(acc[f][g][3]);
                    *(ushort4*)(vt + ((size_t)bb * 1024 + gn) * SEQ + s0) = pk;
                }
            }
        }
        return;
    }

#pragma unroll
    for (int g = 0; g < 4; ++g) {
        int gn = cn + g * 16;
        float bj = bias ? bias[gn] : 0.f;
#pragma unroll
        for (int f = 0; f < 8; ++f)
#pragma unroll
            for (int r = 0; r < 4; ++r) {
                float vv = acc[f][g][r] + bj;
                if (do_gelu) vv = gelu_f(vv);
                Cb[(size_t)(cm0 + f * 16 + r) * N + gn] = f2bf(vv);
            }
    }
}

// ---------------- bf16 MFMA GEMM, double-buffered BK=32, 128x128 (split-K fp32) -------
__global__ __launch_bounds__(256) void gemm_bf16_kernel(
    const unsigned short* __restrict__ A,   // [M,K] bf16
    const unsigned short* __restrict__ Bt,  // [N,K] bf16
    float* __restrict__ Cf0,
    float* __restrict__ Cf1,
    int M, int N, int K, int Klen)
{
    __shared__ short As[2][4096];   // 8 KiB per buffer
    __shared__ short Bs[2][4096];

    int tid = threadIdx.x;
    int m0 = blockIdx.y * 128;
    int n0 = blockIdx.x * 128;
    int k0 = blockIdx.z * Klen;
    float* Cf = blockIdx.z ? Cf1 : Cf0;
    int wv = tid >> 6, lane = tid & 63;
    int wr = wv >> 1, wc = wv & 1;
    int quad = lane >> 4, ln = lane & 15;

    f4v acc[4][4];
#pragma unroll
    for (int i = 0; i < 4; ++i)
#pragma unroll
        for (int j = 0; j < 4; ++j) {
            f4v z = {0.f, 0.f, 0.f, 0.f};
            acc[i][j] = z;
        }

    int r0 = tid & 127;
    size_t Kby = (size_t)K << 1;
    const char* Ag0 = (const char*)A + (size_t)(m0 + r0) * Kby + (size_t)k0 * 2 + (tid >> 7) * 16;
    const char* Bg0 = (const char*)Bt + (size_t)(n0 + r0) * Kby + (size_t)k0 * 2 + (tid >> 7) * 16;

    int nIter = Klen >> 5;
    GLDS(Ag0, (char*)As[0] + tid * 16);
    GLDS(Ag0 + 32, (char*)As[0] + tid * 16 + 4096);
    GLDS(Bg0, (char*)Bs[0] + tid * 16);
    GLDS(Bg0 + 32, (char*)Bs[0] + tid * 16 + 4096);

    for (int it = 0; it < nIter; ++it) {
        __syncthreads();
        if (it + 1 < nIter) {
            int kb = (it + 1) << 6;
            char* Ad = (char*)As[(it + 1) & 1] + tid * 16;
            char* Bd = (char*)Bs[(it + 1) & 1] + tid * 16;
            GLDS(Ag0 + kb, Ad);
            GLDS(Ag0 + kb + 32, Ad + 4096);
            GLDS(Bg0 + kb, Bd);
            GLDS(Bg0 + kb + 32, Bd + 4096);
        }
        const short* Ab = As[it & 1];
        const short* Bb = Bs[it & 1];
        s8v af[4], bfr[4];
#pragma unroll
        for (int i = 0; i < 4; ++i)
            af[i] = *(const s8v*)(Ab + ((size_t)quad * 128 + wr * 64 + i * 16 + ln) * 8);
#pragma unroll
        for (int j = 0; j < 4; ++j)
            bfr[j] = *(const s8v*)(Bb + ((size_t)quad * 128 + wc * 64 + j * 16 + ln) * 8);
#pragma unroll
        for (int i = 0; i < 4; ++i)
#pragma unroll
            for (int j = 0; j < 4; ++j)
                acc[i][j] = __builtin_amdgcn_mfma_f32_16x16x32_bf16(af[i], bfr[j], acc[i][j], 0, 0, 0);
    }

    int cn  = n0 + wc * 64 + ln;
    int cm0 = m0 + wr * 64 + quad * 4;
#pragma unroll
    for (int j = 0; j < 4; ++j) {
        int gn = cn + j * 16;
#pragma unroll
        for (int i = 0; i < 4; ++i)
#pragma unroll
            for (int r = 0; r < 4; ++r)
                Cf[(size_t)(cm0 + i * 16 + r) * N + gn] = acc[i][j][r];
    }
}

// ---------------- double-buffered MFMA flash attention (unchanged) --------------------
__global__ __launch_bounds__(256) void flash_attn_mfma_kernel(
    const unsigned short* __restrict__ qk,   // [NTOK][2048]  (q*scale | k per head)
    const unsigned short* __restrict__ vt,   // [B*1024][SEQ] (v transposed)
    unsigned short* __restrict__ ctx)        // [NTOK][EMB]
{
    int h  = blockIdx.x;
    int qt = (int)gridDim.y - 1 - (int)blockIdx.y;
    int b  = blockIdx.z;
    int tid = threadIdx.x;
    int w = tid >> 6, lane = tid & 63;
    int quad = lane >> 4, ln = lane & 15;

    __shared__ short Kb2[2][4096];
    __shared__ short Vb2[2][4096];
    __shared__ short Ps[4][32 * 72];

    size_t qrow0 = (size_t)b * SEQ + (size_t)qt * 128;
    int wrow0 = w * 32;

    s8v qf[2][2];
#pragma unroll
    for (int mb = 0; mb < 2; ++mb)
#pragma unroll
        for (int ks = 0; ks < 2; ++ks)
            qf[mb][ks] = *(const s8v*)(qk + (qrow0 + wrow0 + mb * 16 + ln) * 2048
                                          + h * 64 + ks * 32 + quad * 8);

    float l_part[2][4];
    f4v o[2][4];
#pragma unroll
    for (int mb = 0; mb < 2; ++mb) {
#pragma unroll
        for (int r = 0; r < 4; ++r) l_part[mb][r] = 0.f;
#pragma unroll
        for (int db = 0; db < 4; ++db) {
            f4v z = {0.f, 0.f, 0.f, 0.f};
            o[mb][db] = z;
        }
    }

    const unsigned short* kb_p = qk + (size_t)b * SEQ * 2048 + 1024 + h * 64;
    const unsigned short* vb_p = vt + ((size_t)b * 1024 + h * 64) * SEQ;
    short* Pw = Ps[w];

    int rr = tid & 63;
    const unsigned short* Kg0 = kb_p + (size_t)rr * 2048 + (tid >> 6) * 8;
    const unsigned short* Vg0 = vb_p + (size_t)rr * 2048 + (tid >> 6) * 8;

    int ktn = 2 * qt + 2;
    int ktmax_w = (qt * 128 + wrow0 + 31) >> 6;

    GLDS(Kg0, (char*)Kb2[0] + tid * 16);
    GLDS(Kg0 + 32, (char*)Kb2[0] + tid * 16 + 4096);
    GLDS(Vg0, (char*)Vb2[0] + tid * 16);
    GLDS(Vg0 + 32, (char*)Vb2[0] + tid * 16 + 4096);

    for (int kt = 0; kt < ktn; ++kt) {
        __syncthreads();
        if (kt + 1 < ktn) {
            int nb_ = (kt + 1) & 1;
            const unsigned short* ks_ = Kg0 + (size_t)(kt + 1) * 64 * 2048;
            const unsigned short* vs_ = Vg0 + (kt + 1) * 64;
            GLDS(ks_, (char*)Kb2[nb_] + tid * 16);
            GLDS(ks_ + 32, (char*)Kb2[nb_] + tid * 16 + 4096);
            GLDS(vs_, (char*)Vb2[nb_] + tid * 16);
            GLDS(vs_ + 32, (char*)Vb2[nb_] + tid * 16 + 4096);
        }
        if (kt > ktmax_w) continue;

        const short* Kl = Kb2[kt & 1];
        const short* Vl = Vb2[kt & 1];

        f4v s[2][4];
#pragma unroll
        for (int mb = 0; mb < 2; ++mb)
#pragma unroll
            for (int nb = 0; nb < 4; ++nb) {
                f4v z = {0.f, 0.f, 0.f, 0.f};
                s[mb][nb] = z;
            }
#pragma unroll
        for (int ks = 0; ks < 2; ++ks)
#pragma unroll
            for (int nb = 0; nb < 4; ++nb) {
                s8v kfr = *(const s8v*)(Kl + ((size_t)(ks * 4 + quad) * 64 + nb * 16 + ln) * 8);
#pragma unroll
                for (int mb = 0; mb < 2; ++mb)
                    s[mb][nb] = __builtin_amdgcn_mfma_f32_16x16x32_bf16(qf[mb][ks], kfr, s[mb][nb], 0, 0, 0);
            }

#pragma unroll
        for (int mb = 0; mb < 2; ++mb) {
#pragma unroll
            for (int r = 0; r < 4; ++r) {
                int rloc = mb * 16 + quad * 4 + r;
                int grow = qt * 128 + wrow0 + rloc;
                float p[4];
#pragma unroll
                for (int nb = 0; nb < 4; ++nb) {
                    int key = kt * 64 + nb * 16 + ln;
                    float e = fast_exp2(s[mb][nb][r]);
                    p[nb] = (key > grow) ? 0.f : e;
                }
                l_part[mb][r] += (p[0] + p[1]) + (p[2] + p[3]);
#pragma unroll
                for (int nb = 0; nb < 4; ++nb)
                    Pw[rloc * 72 + nb * 16 + ln] = f2bf(p[nb]);
            }
        }

#pragma unroll
        for (int ks = 0; ks < 2; ++ks) {
            s8v pf[2];
#pragma unroll
            for (int mb = 0; mb < 2; ++mb)
                pf[mb] = *(const s8v*)(Pw + (mb * 16 + ln) * 72 + ks * 32 + quad * 8);
#pragma unroll
            for (int db = 0; db < 4; ++db) {
                s8v vfr = *(const s8v*)(Vl + ((size_t)(ks * 4 + quad) * 64 + db * 16 + ln) * 8);
#pragma unroll
                for (int mb = 0; mb < 2; ++mb)
                    o[mb][db] = __builtin_amdgcn_mfma_f32_16x16x32_bf16(pf[mb], vfr, o[mb][db], 0, 0, 0);
            }
        }
    }

#pragma unroll
    for (int mb = 0; mb < 2; ++mb)
#pragma unroll
        for (int r = 0; r < 4; ++r) {
            float l = l_part[mb][r];
#pragma unroll
            for (int msk = 1; msk < 16; msk <<= 1)
                l += __shfl_xor(l, msk);
            float inv = 1.0f / l;
            size_t row = qrow0 + wrow0 + mb * 16 + quad * 4 + r;
#pragma unroll
            for (int db = 0; db < 4; ++db)
                ctx[row * EMB + h * 64 + db * 16 + ln] = f2bf(o[mb][db][r] * inv);
        }
}

extern "C" void kernel_launch(void* const* d_in, const int* in_sizes, int n_in,
                              void* d_out, int out_size, void* d_ws, size_t ws_size,
                              hipStream_t stream) {
    const float* x    = (const float*)d_in[0];
    const float* Wq   = (const float*)d_in[1];
    const float* Wk   = (const float*)d_in[2];
    const float* Wv   = (const float*)d_in[3];
    const float* Wo   = (const float*)d_in[4];
    const float* bo   = (const float*)d_in[5];
    const float* W1   = (const float*)d_in[6];
    const float* b1   = (const float*)d_in[7];
    const float* W2   = (const float*)d_in[8];
    const float* b2   = (const float*)d_in[9];
    const float* ln1s = (const float*)d_in[10];
    const float* ln1b = (const float*)d_in[11];
    const float* ln2s = (const float*)d_in[12];
    const float* ln2b = (const float*)d_in[13];
    float* out = (float*)d_out;

    const size_t MiB = 1024 * 1024;
    uint8_t* w8 = (uint8_t*)d_ws;
    unsigned short* Wqkv_t = (unsigned short*)(w8);             //  0..6   [3072][1024]
    unsigned short* Wo_t   = (unsigned short*)(w8 +  6 * MiB);  //  6..8   [1024][1024]
    unsigned short* W1_t   = (unsigned short*)(w8 +  8 * MiB);  //  8..16  [4096][1024]
    unsigned short* W2_t   = (unsigned short*)(w8 + 16 * MiB);  // 16..24  [1024][4096]
    unsigned short* act_bf = (unsigned short*)(w8 + 24 * MiB);  // 24..32  h1/ctx/h2
    unsigned short* qk_bf  = (unsigned short*)(w8 + 32 * MiB);  // 32..48  [4096][2048]
    unsigned short* vt     = (unsigned short*)(w8 + 48 * MiB);  // 48..56  [2048][2048]
    float*          p0a    = (float*)(w8 + 32 * MiB);           // 32..48  (after attn)
    float*          p1a    = (float*)(w8 + 48 * MiB);           // 48..64
    unsigned short* u_bf   = (unsigned short*)(w8 + 32 * MiB);  // 32..64  (step 6+)
    float*          x1     = (float*)(w8 + 64 * MiB);           // 64..80
    float*          p0b    = (float*)(w8);                      //  0..16  (weights dead)
    float*          p1b    = (float*)(w8 + 80 * MiB);           // 80..96

    // 0) all weight converts in one dispatch
    tconv_all_kernel<<<3072, 256, 0, stream>>>(Wq, Wk, Wv, Wo, W1, W2,
                                               Wqkv_t, Wo_t, W1_t, W2_t);

    // 1) LN1 -> bf16
    ln_bf16_kernel<<<NTOK, 256, 0, stream>>>(x, ln1s, ln1b, act_bf);

    // 2) fused QKV (8-phase 256x256; q prescaled, q/k row-major bf16, v -> vt)
    gemm_8ph_kernel<<<(NTOK / 256) * (QKV_N / 256), 512, 0, stream>>>(
        act_bf, Wqkv_t, qk_bf, NTOK, QKV_N, EMB, nullptr, 0, 1, vt);

    // 3) double-buffered MFMA flash attention -> ctx bf16
    flash_attn_mfma_kernel<<<dim3(HEADS, SEQ / 128, BATCH), 256, 0, stream>>>(qk_bf, vt, act_bf);

    // 4+5) x1 = x + ctx @ Wo + bo (split-K2); fused reduce+LN2
    gemm_bf16_kernel<<<dim3(EMB / 128, NTOK / 128, 2), 256, 0, stream>>>(
        act_bf, Wo_t, p0a, p1a, NTOK, EMB, EMB, 512);
    reduce_ln_kernel<<<NTOK, 256, 0, stream>>>(p0a, p1a, bo, x, x1, ln2s, ln2b, act_bf);

    // 6) u = gelu(h2 @ W1 + b1) -> bf16  (8-phase 256x256)
    gemm_8ph_kernel<<<(NTOK / 256) * (FF_DIM / 256), 512, 0, stream>>>(
        act_bf, W1_t, u_bf, NTOK, FF_DIM, EMB, b1, 1, 0, nullptr);

    // 7) out = x1 + u @ W2 + b2   (split-K2)
    gemm_bf16_kernel<<<dim3(EMB / 128, NTOK / 128, 2), 256, 0, stream>>>(
        u_bf, W2_t, p0b, p1b, NTOK, EMB, FF_DIM, 2048);
    reduce_kernel<<<(NTOK * EMB) / 1024, 256, 0, stream>>>(p0b, p1b, b2, x1, out);
}

// Round 2
// 422.177 us; speedup vs baseline: 1.1187x; 1.0138x over previous
//
#include <hip/hip_runtime.h>
#include <hip/hip_bf16.h>
#include <math.h>

#define EMB 1024
#define HEADS 16
#define HEAD_DIM 64
#define FF_DIM 4096
#define SEQ 2048
#define BATCH 2
#define NTOK (BATCH * SEQ)   // 4096 rows
#define LN_EPS 1e-5f
#define QKV_N 3072
// fold softmax scale into q: 0.125 * log2(e)
#define Q_PRESCALE 0.18033688011112042f

typedef __attribute__((ext_vector_type(8))) short s8v;   // 8 bf16 (4 VGPRs)
typedef __attribute__((ext_vector_type(4))) float f4v;   // MFMA accumulator

__device__ __forceinline__ unsigned short f2bf(float f) {
    union { __hip_bfloat16 h; unsigned short u; } cv;
    cv.h = __float2bfloat16(f);
    return cv.u;
}

__device__ __forceinline__ float fast_exp2(float x) {
#if __has_builtin(__builtin_amdgcn_exp2f)
    return __builtin_amdgcn_exp2f(x);
#else
    return exp2f(x);
#endif
}

__device__ __forceinline__ float gelu_f(float x) {
    const float c = 0.7978845608028654f;  // sqrt(2/pi)
    float x3 = x * x * x;
    return 0.5f * x * (1.0f + tanhf(c * (x + 0.044715f * x3)));
}

#define GLDS(gp, lp)                                                        \
    __builtin_amdgcn_global_load_lds(                                       \
        (const __attribute__((address_space(1))) void*)(gp),                \
        (__attribute__((address_space(3))) void*)(lp), 16, 0, 0)

// sync helpers (raw barrier: no compiler vmcnt(0) drain)
#define BAR()   do { __builtin_amdgcn_s_barrier(); __builtin_amdgcn_sched_barrier(0); } while (0)
#define LGKM0() do { asm volatile("s_waitcnt lgkmcnt(0)" ::: "memory"); __builtin_amdgcn_sched_barrier(0); } while (0)
#define VMCNT(n) do { asm volatile("s_waitcnt vmcnt(" #n ")" ::: "memory"); __builtin_amdgcn_sched_barrier(0); } while (0)

// ---------------- LayerNorm -> bf16 out ----------------------------------------------
__global__ __launch_bounds__(256) void ln_bf16_kernel(const float* __restrict__ x,
                                                      const float* __restrict__ scale,
                                                      const float* __restrict__ shift,
                                                      unsigned short* __restrict__ out) {
    int row = blockIdx.x;
    int tid = threadIdx.x;
    const float4 xv = ((const float4*)(x + (size_t)row * EMB))[tid];
    float s  = xv.x + xv.y + xv.z + xv.w;
    float ss = xv.x * xv.x + xv.y * xv.y + xv.z * xv.z + xv.w * xv.w;
    __shared__ float2 red[256];
    red[tid] = make_float2(s, ss);
    __syncthreads();
    for (int off = 128; off > 0; off >>= 1) {
        if (tid < off) {
            red[tid].x += red[tid + off].x;
            red[tid].y += red[tid + off].y;
        }
        __syncthreads();
    }
    float mean = red[0].x * (1.0f / EMB);
    float var  = red[0].y * (1.0f / EMB) - mean * mean;
    float rstd = rsqrtf(var + LN_EPS);
    float4 sc4 = ((const float4*)scale)[tid];
    float4 sh4 = ((const float4*)shift)[tid];
    ushort4 o;
    o.x = f2bf(sc4.x * (xv.x - mean) * rstd + sh4.x);
    o.y = f2bf(sc4.y * (xv.y - mean) * rstd + sh4.y);
    o.z = f2bf(sc4.z * (xv.z - mean) * rstd + sh4.z);
    o.w = f2bf(sc4.w * (xv.w - mean) * rstd + sh4.w);
    *(ushort4*)(out + (size_t)row * EMB + tid * 4) = o;
}

// ---------------- fused fp32 [K][N] -> bf16 [N][K] transpose-convert (ALL weights) ----
__device__ __forceinline__ void tconv_tile(const float* __restrict__ W,
                                           unsigned short* __restrict__ Wt,
                                           int K, int N, int bx, int by, int tid) {
    __shared__ float t[64][65];
    int n0 = bx * 64, k0 = by * 64;
#pragma unroll
    for (int it = 0; it < 4; ++it) {
        int f = tid + it * 256;
        int r = f >> 4, c = (f & 15) * 4;
        float4 w = *(const float4*)(W + (size_t)(k0 + r) * N + n0 + c);
        t[r][c] = w.x; t[r][c + 1] = w.y; t[r][c + 2] = w.z; t[r][c + 3] = w.w;
    }
    __syncthreads();
#pragma unroll
    for (int it = 0; it < 4; ++it) {
        int f = tid + it * 256;
        int rn = f >> 4, ck = (f & 15) * 4;
        ushort4 o;
        o.x = f2bf(t[ck + 0][rn]);
        o.y = f2bf(t[ck + 1][rn]);
        o.z = f2bf(t[ck + 2][rn]);
        o.w = f2bf(t[ck + 3][rn]);
        *(ushort4*)(Wt + (size_t)(n0 + rn) * K + k0 + ck) = o;
    }
}

__global__ __launch_bounds__(256) void tconv_all_kernel(
    const float* __restrict__ Wq, const float* __restrict__ Wk,
    const float* __restrict__ Wv, const float* __restrict__ Wo,
    const float* __restrict__ W1, const float* __restrict__ W2,
    unsigned short* __restrict__ Wqkv_t, unsigned short* __restrict__ Wo_t,
    unsigned short* __restrict__ W1_t, unsigned short* __restrict__ W2_t) {
    int b = blockIdx.x;
    int tid = threadIdx.x;
    if (b < 256)        tconv_tile(Wq, Wqkv_t,                      EMB, EMB,    b & 15, b >> 4, tid);
    else if (b < 512)   tconv_tile(Wk, Wqkv_t + (size_t)1024 * EMB, EMB, EMB,    (b - 256) & 15, (b - 256) >> 4, tid);
    else if (b < 768)   tconv_tile(Wv, Wqkv_t + (size_t)2048 * EMB, EMB, EMB,    (b - 512) & 15, (b - 512) >> 4, tid);
    else if (b < 1024)  tconv_tile(Wo, Wo_t,                        EMB, EMB,    (b - 768) & 15, (b - 768) >> 4, tid);
    else if (b < 2048)  tconv_tile(W1, W1_t,                        EMB, FF_DIM, (b - 1024) & 63, (b - 1024) >> 6, tid);
    else                tconv_tile(W2, W2_t,                        FF_DIM, EMB, (b - 2048) & 15, (b - 2048) >> 4, tid);
}

// ---------------- split-K reduce: out = p0 + p1 + bias + residual ---------------------
__global__ __launch_bounds__(256) void reduce_kernel(const float* __restrict__ p0,
                                                     const float* __restrict__ p1,
                                                     const float* __restrict__ bias,
                                                     const float* __restrict__ residual,
                                                     float* __restrict__ out) {
    size_t i4 = ((size_t)blockIdx.x * 256 + threadIdx.x) * 4;
    float4 a = *(const float4*)(p0 + i4);
    float4 b = *(const float4*)(p1 + i4);
    float4 r = *(const float4*)(residual + i4);
    int col = (int)(i4 & (EMB - 1));
    float4 bs = *(const float4*)(bias + col);
    float4 o;
    o.x = a.x + b.x + r.x + bs.x;
    o.y = a.y + b.y + r.y + bs.y;
    o.z = a.z + b.z + r.z + bs.z;
    o.w = a.w + b.w + r.w + bs.w;
    *(float4*)(out + i4) = o;
}

// ---------------- fused split-K reduce + LayerNorm ------------------------------------
__global__ __launch_bounds__(256) void reduce_ln_kernel(const float* __restrict__ p0,
                                                        const float* __restrict__ p1,
                                                        const float* __restrict__ bias,
                                                        const float* __restrict__ residual,
                                                        float* __restrict__ x1,
                                                        const float* __restrict__ scale,
                                                        const float* __restrict__ shift,
                                                        unsigned short* __restrict__ out) {
    int row = blockIdx.x;
    int tid = threadIdx.x;
    size_t i4 = (size_t)row * EMB + tid * 4;
    float4 a = *(const float4*)(p0 + i4);
    float4 b = *(const float4*)(p1 + i4);
    float4 r = *(const float4*)(residual + i4);
    float4 bs = *(const float4*)(bias + tid * 4);
    float4 xv;
    xv.x = a.x + b.x + r.x + bs.x;
    xv.y = a.y + b.y + r.y + bs.y;
    xv.z = a.z + b.z + r.z + bs.z;
    xv.w = a.w + b.w + r.w + bs.w;
    *(float4*)(x1 + i4) = xv;

    float s  = xv.x + xv.y + xv.z + xv.w;
    float ss = xv.x * xv.x + xv.y * xv.y + xv.z * xv.z + xv.w * xv.w;
    __shared__ float2 red[256];
    red[tid] = make_float2(s, ss);
    __syncthreads();
    for (int off = 128; off > 0; off >>= 1) {
        if (tid < off) {
            red[tid].x += red[tid + off].x;
            red[tid].y += red[tid + off].y;
        }
        __syncthreads();
    }
    float mean = red[0].x * (1.0f / EMB);
    float var  = red[0].y * (1.0f / EMB) - mean * mean;
    float rstd = rsqrtf(var + LN_EPS);
    float4 sc4 = ((const float4*)scale)[tid];
    float4 sh4 = ((const float4*)shift)[tid];
    ushort4 o;
    o.x = f2bf(sc4.x * (xv.x - mean) * rstd + sh4.x);
    o.y = f2bf(sc4.y * (xv.y - mean) * rstd + sh4.y);
    o.z = f2bf(sc4.z * (xv.z - mean) * rstd + sh4.z);
    o.w = f2bf(sc4.w * (xv.w - mean) * rstd + sh4.w);
    *(ushort4*)(out + i4) = o;
}

// ================= 8-phase 256x256 bf16 MFMA GEMM (HK schedule, plain HIP) ============
// (unchanged from round 1 -- awaiting counters before touching)
__global__ __launch_bounds__(512, 2) void gemm_8ph_kernel(
    const unsigned short* __restrict__ A,   // [M,K] bf16
    const unsigned short* __restrict__ Bt,  // [N,K] bf16
    unsigned short* __restrict__ Cb,        // bf16 out
    int M, int N, int K,
    const float* __restrict__ bias,
    int do_gelu, int qkv_mode,
    unsigned short* __restrict__ vt)
{
    __shared__ short lds[65536];   // 128 KiB: A at [0,64K), B at [64K,128K) bytes

    int tid = threadIdx.x;
    int w = tid >> 6, lane = tid & 63;
    int wr = w >> 2, wc = w & 3;          // wave rows wr*128.., cols wc*64..
    int quad = lane >> 4, ln = lane & 15;

    // XCD-bijective block swizzle (nwg % 8 == 0 for both call sites)
    int nbx = N >> 8;
    int nwg = (M >> 8) * nbx;
    int bid = (int)blockIdx.x;
    int swz = (nwg & 7) ? bid : ((bid & 7) * (nwg >> 3) + (bid >> 3));
    int by = swz / nbx, bx = swz - by * nbx;
    int m0 = by << 8, n0 = bx << 8;

    f4v acc[8][4];
#pragma unroll
    for (int i = 0; i < 8; ++i)
#pragma unroll
        for (int j = 0; j < 4; ++j) { f4v z = {0.f, 0.f, 0.f, 0.f}; acc[i][j] = z; }

    size_t Kby = (size_t)K << 1;
    size_t AhS = (size_t)128 * Kby;       // half-tile row-block stride (A and B)
    const char* AgC = (const char*)A + (size_t)(m0 + (tid & 127)) * Kby + (size_t)((tid >> 7) << 4);
    const char* BgC = (const char*)Bt + (size_t)(n0 + (tid & 127)) * Kby + (size_t)((tid >> 7) << 4);
    char* ldsC = (char*)lds;
    int tid16 = tid << 4;

    // frag read bases (shorts): A[buf][half=wr][kc=ks*4+quad][row=f*16+ln][8]
    const short* aRd = lds + wr * 8192 + quad * 1024 + ln * 8;
    const short* bRd = lds + 32768 + (wc >> 1) * 8192 + (wc & 1) * 512 + quad * 1024 + ln * 8;

#define STG_A(tb, h, b) do {                                                     \
    const char* s_ = AgC + (size_t)(h) * AhS + (size_t)(tb);                     \
    char* d_ = ldsC + (b) * 32768 + (h) * 16384 + tid16;                         \
    GLDS(s_, d_); GLDS(s_ + 64, d_ + 8192); } while (0)
#define STG_B(tb, h, b) do {                                                     \
    const char* s_ = BgC + (size_t)(h) * AhS + (size_t)(tb);                     \
    char* d_ = ldsC + 65536 + (b) * 32768 + (h) * 16384 + tid16;                 \
    GLDS(s_, d_); GLDS(s_ + 64, d_ + 8192); } while (0)
#define RD_A4(mg, b) do {                                                        \
    _Pragma("unroll") for (int f_ = 0; f_ < 4; ++f_) {                           \
        af[f_][0] = *(const s8v*)(aRd + (b) * 16384 + ((mg) * 4 + f_) * 128);    \
        af[f_][1] = *(const s8v*)(aRd + (b) * 16384 + 4096 + ((mg) * 4 + f_) * 128); } } while (0)
#define RD_B2(dst, ng, b) do {                                                   \
    _Pragma("unroll") for (int g_ = 0; g_ < 2; ++g_) {                           \
        dst[g_][0] = *(const s8v*)(bRd + (b) * 16384 + ((ng) * 2 + g_) * 128);   \
        dst[g_][1] = *(const s8v*)(bRd + (b) * 16384 + 4096 + ((ng) * 2 + g_) * 128); } } while (0)
#define MF_Q(mg, bsrc, ng) do {                                                  \
    __builtin_amdgcn_s_setprio(1);                                               \
    _Pragma("unroll") for (int f_ = 0; f_ < 4; ++f_)                             \
    _Pragma("unroll") for (int g_ = 0; g_ < 2; ++g_)                             \
    _Pragma("unroll") for (int k_ = 0; k_ < 2; ++k_)                             \
        acc[(mg) * 4 + f_][(ng) * 2 + g_] = __builtin_amdgcn_mfma_f32_16x16x32_bf16( \
            af[f_][k_], bsrc[g_][k_], acc[(mg) * 4 + f_][(ng) * 2 + g_], 0, 0, 0); \
    __builtin_amdgcn_s_setprio(0); } while (0)

    s8v af[4][2], bf0[2][2], bf1[2][2];

    // prologue: tile0 fully + tile1 B-halves (12 loads); wait keeps tile1 B in flight
    STG_A(0, 0, 0); STG_A(0, 1, 0);
    STG_B(0, 0, 0); STG_B(0, 1, 0);
    STG_B(128, 0, 1); STG_B(128, 1, 1);
    VMCNT(4);
    BAR();

    int nIter = K >> 7;   // K multiple of 128
    for (int it = 0; it < nIter; ++it) {
        size_t base = (size_t)it << 8;    // tile 2it byte offset in K
        bool pf = (it + 1 < nIter);

        // ---- K-tile T0 = 2it (buf0) ----
        // P1: quadrant (m0,n0)
        RD_A4(0, 0); RD_B2(bf0, 0, 0);
        STG_A(base + 128, 0, 1);
        BAR(); LGKM0();
        MF_Q(0, bf0, 0);
        BAR();
        // P2: (m0,n1)
        RD_B2(bf1, 1, 0);
        STG_A(base + 128, 1, 1);
        BAR(); LGKM0();
        MF_Q(0, bf1, 1);
        BAR();
        // P3: (m1,n0)
        RD_A4(1, 0);
        if (pf) STG_B(base + 256, 0, 0);
        BAR(); LGKM0();
        MF_Q(1, bf0, 0);
        BAR();
        // P4: (m1,n1); counted wait covers tile T1 for P5..P8
        if (pf) STG_B(base + 256, 1, 0);
        BAR();
        MF_Q(1, bf1, 1);
        if (pf) { VMCNT(4); } else { VMCNT(0); }
        BAR();

        // ---- K-tile T1 = 2it+1 (buf1) ----
        // P5
        RD_A4(0, 1); RD_B2(bf0, 0, 1);
        if (pf) STG_A(base + 256, 0, 0);
        BAR(); LGKM0();
        MF_Q(0, bf0, 0);
        BAR();
        // P6
        RD_B2(bf1, 1, 1);
        if (pf) STG_A(base + 256, 1, 0);
        BAR(); LGKM0();
        MF_Q(0, bf1, 1);
        BAR();
        // P7
        RD_A4(1, 1);
        if (pf) STG_B(base + 384, 0, 1);
        BAR(); LGKM0();
        MF_Q(1, bf0, 0);
        BAR();
        // P8: counted wait covers tile T0+2 for next iteration's P1..P4
        if (pf) STG_B(base + 384, 1, 1);
        BAR();
        MF_Q(1, bf1, 1);
        if (pf) VMCNT(4);
        BAR();
    }
#undef STG_A
#undef STG_B
#undef RD_A4
#undef RD_B2
#undef MF_Q

    // epilogue: C/D layout col=lane&15, row=(lane>>4)*4+reg
    int cn  = n0 + wc * 64 + ln;
    int cm0 = m0 + wr * 128 + quad * 4;

    if (qkv_mode) {
        if (n0 < 2048) {
            float sc = (n0 < 1024) ? Q_PRESCALE : 1.0f;
#pragma unroll
            for (int g = 0; g < 4; ++g) {
                int gn = cn + g * 16;
#pragma unroll
                for (int f = 0; f < 8; ++f)
#pragma unroll
                    for (int r = 0; r < 4; ++r)
                        Cb[(size_t)(cm0 + f * 16 + r) * 2048 + gn] = f2bf(acc[f][g][r] * sc);
            }
        } else {
#pragma unroll
            for (int g = 0; g < 4; ++g) {
                int gn = cn + g * 16 - 2048;       // h*64+d in [0,1024)
#pragma unroll
                for (int f = 0; f < 8; ++f) {
                    int gm0 = cm0 + f * 16;
                    int bb = gm0 >> 11, s0 = gm0 & 2047;
                    ushort4 pk;
                    pk.x = f2bf(acc[f][g][0]);
                    pk.y = f2bf(acc[f][g][1]);
                    pk.z = f2bf(acc[f][g][2]);
                    pk.w = f2bf(acc[f][g][3]);
                    *(ushort4*)(vt + ((size_t)bb * 1024 + gn) * SEQ + s0) = pk;
                }
            }
        }
        return;
    }

#pragma unroll
    for (int g = 0; g < 4; ++g) {
        int gn = cn + g * 16;
        float bj = bias ? bias[gn] : 0.f;
#pragma unroll
        for (int f = 0; f < 8; ++f)
#pragma unroll
            for (int r = 0; r < 4; ++r) {
                float vv = acc[f][g][r] + bj;
                if (do_gelu) vv = gelu_f(vv);
                Cb[(size_t)(cm0 + f * 16 + r) * N + gn] = f2bf(vv);
            }
    }
}

// ---------------- bf16 MFMA GEMM, double-buffered BK=32, 128x128 (split-K fp32) -------
__global__ __launch_bounds__(256) void gemm_bf16_kernel(
    const unsigned short* __restrict__ A,   // [M,K] bf16
    const unsigned short* __restrict__ Bt,  // [N,K] bf16
    float* __restrict__ Cf0,
    float* __restrict__ Cf1,
    int M, int N, int K, int Klen)
{
    __shared__ short As[2][4096];   // 8 KiB per buffer
    __shared__ short Bs[2][4096];

    int tid = threadIdx.x;
    int m0 = blockIdx.y * 128;
    int n0 = blockIdx.x * 128;
    int k0 = blockIdx.z * Klen;
    float* Cf = blockIdx.z ? Cf1 : Cf0;
    int wv = tid >> 6, lane = tid & 63;
    int wr = wv >> 1, wc = wv & 1;
    int quad = lane >> 4, ln = lane & 15;

    f4v acc[4][4];
#pragma unroll
    for (int i = 0; i < 4; ++i)
#pragma unroll
        for (int j = 0; j < 4; ++j) {
            f4v z = {0.f, 0.f, 0.f, 0.f};
            acc[i][j] = z;
        }

    int r0 = tid & 127;
    size_t Kby = (size_t)K << 1;
    const char* Ag0 = (const char*)A + (size_t)(m0 + r0) * Kby + (size_t)k0 * 2 + (tid >> 7) * 16;
    const char* Bg0 = (const char*)Bt + (size_t)(n0 + r0) * Kby + (size_t)k0 * 2 + (tid >> 7) * 16;

    int nIter = Klen >> 5;
    GLDS(Ag0, (char*)As[0] + tid * 16);
    GLDS(Ag0 + 32, (char*)As[0] + tid * 16 + 4096);
    GLDS(Bg0, (char*)Bs[0] + tid * 16);
    GLDS(Bg0 + 32, (char*)Bs[0] + tid * 16 + 4096);

    for (int it = 0; it < nIter; ++it) {
        __syncthreads();
        if (it + 1 < nIter) {
            int kb = (it + 1) << 6;
            char* Ad = (char*)As[(it + 1) & 1] + tid * 16;
            char* Bd = (char*)Bs[(it + 1) & 1] + tid * 16;
            GLDS(Ag0 + kb, Ad);
            GLDS(Ag0 + kb + 32, Ad + 4096);
            GLDS(Bg0 + kb, Bd);
            GLDS(Bg0 + kb + 32, Bd + 4096);
        }
        const short* Ab = As[it & 1];
        const short* Bb = Bs[it & 1];
        s8v af[4], bfr[4];
#pragma unroll
        for (int i = 0; i < 4; ++i)
            af[i] = *(const s8v*)(Ab + ((size_t)quad * 128 + wr * 64 + i * 16 + ln) * 8);
#pragma unroll
        for (int j = 0; j < 4; ++j)
            bfr[j] = *(const s8v*)(Bb + ((size_t)quad * 128 + wc * 64 + j * 16 + ln) * 8);
#pragma unroll
        for (int i = 0; i < 4; ++i)
#pragma unroll
            for (int j = 0; j < 4; ++j)
                acc[i][j] = __builtin_amdgcn_mfma_f32_16x16x32_bf16(af[i], bfr[j], acc[i][j], 0, 0, 0);
    }

    int cn  = n0 + wc * 64 + ln;
    int cm0 = m0 + wr * 64 + quad * 4;
#pragma unroll
    for (int j = 0; j < 4; ++j) {
        int gn = cn + j * 16;
#pragma unroll
        for (int i = 0; i < 4; ++i)
#pragma unroll
            for (int r = 0; r < 4; ++r)
                Cf[(size_t)(cm0 + i * 16 + r) * N + gn] = acc[i][j][r];
    }
}

// ---------------- double-buffered MFMA flash attention --------------------------------
// R2 changes: (1) causal load-balance -- co-resident block pair (b=0/1, same h,y)
// now covers qt = {15-y, y} so every CU carries a uniform 36 key-tile units;
// (2) raw s_barrier + counted vmcnt(8) instead of __syncthreads' vmcnt(0) drain;
// (3) mask-free fast path for interior tiles (mask needed only at kt == ktmax_w).
__global__ __launch_bounds__(256) void flash_attn_mfma_kernel(
    const unsigned short* __restrict__ qk,   // [NTOK][2048]  (q*scale | k per head)
    const unsigned short* __restrict__ vt,   // [B*1024][SEQ] (v transposed)
    unsigned short* __restrict__ ctx)        // [NTOK][EMB]
{
    int h  = blockIdx.x;
    int b  = blockIdx.z;
    // balance: b=0 -> qt=15-y (long first), b=1 -> qt=y; pair work sums to 36 units
    int qt = b ? (int)blockIdx.y : ((int)gridDim.y - 1 - (int)blockIdx.y);
    int tid = threadIdx.x;
    int w = tid >> 6, lane = tid & 63;
    int quad = lane >> 4, ln = lane & 15;

    __shared__ short Kb2[2][4096];
    __shared__ short Vb2[2][4096];
    __shared__ short Ps[4][32 * 72];

    size_t qrow0 = (size_t)b * SEQ + (size_t)qt * 128;
    int wrow0 = w * 32;

    s8v qf[2][2];
#pragma unroll
    for (int mb = 0; mb < 2; ++mb)
#pragma unroll
        for (int ks = 0; ks < 2; ++ks)
            qf[mb][ks] = *(const s8v*)(qk + (qrow0 + wrow0 + mb * 16 + ln) * 2048
                                          + h * 64 + ks * 32 + quad * 8);

    float l_part[2][4];
    f4v o[2][4];
#pragma unroll
    for (int mb = 0; mb < 2; ++mb) {
#pragma unroll
        for (int r = 0; r < 4; ++r) l_part[mb][r] = 0.f;
#pragma unroll
        for (int db = 0; db < 4; ++db) {
            f4v z = {0.f, 0.f, 0.f, 0.f};
            o[mb][db] = z;
        }
    }

    const unsigned short* kb_p = qk + (size_t)b * SEQ * 2048 + 1024 + h * 64;
    const unsigned short* vb_p = vt + ((size_t)b * 1024 + h * 64) * SEQ;
    short* Pw = Ps[w];

    int rr = tid & 63;
    const unsigned short* Kg0 = kb_p + (size_t)rr * 2048 + (tid >> 6) * 8;
    const unsigned short* Vg0 = vb_p + (size_t)rr * 2048 + (tid >> 6) * 8;

    int ktn = 2 * qt + 2;
    int ktmax_w = (qt * 128 + wrow0 + 31) >> 6;

    GLDS(Kg0, (char*)Kb2[0] + tid * 16);
    GLDS(Kg0 + 32, (char*)Kb2[0] + tid * 16 + 4096);
    GLDS(Vg0, (char*)Vb2[0] + tid * 16);
    GLDS(Vg0 + 32, (char*)Vb2[0] + tid * 16 + 4096);

    for (int kt = 0; kt < ktn; ++kt) {
        BAR();
        bool pf = (kt + 1 < ktn);
        if (pf) {
            int nb_ = (kt + 1) & 1;
            const unsigned short* ks_ = Kg0 + (size_t)(kt + 1) * 64 * 2048;
            const unsigned short* vs_ = Vg0 + (kt + 1) * 64;
            GLDS(ks_, (char*)Kb2[nb_] + tid * 16);
            GLDS(ks_ + 32, (char*)Kb2[nb_] + tid * 16 + 4096);
            GLDS(vs_, (char*)Vb2[nb_] + tid * 16);
            GLDS(vs_ + 32, (char*)Vb2[nb_] + tid * 16 + 4096);
        }
        if (kt > ktmax_w) continue;
        // counted wait: force only THIS tile's loads (prefetch stays in flight)
        if (pf) { VMCNT(8); } else { VMCNT(0); }

        const short* Kl = Kb2[kt & 1];
        const short* Vl = Vb2[kt & 1];

        f4v s[2][4];
#pragma unroll
        for (int mb = 0; mb < 2; ++mb)
#pragma unroll
            for (int nb = 0; nb < 4; ++nb) {
                f4v z = {0.f, 0.f, 0.f, 0.f};
                s[mb][nb] = z;
            }
#pragma unroll
        for (int ks = 0; ks < 2; ++ks)
#pragma unroll
            for (int nb = 0; nb < 4; ++nb) {
                s8v kfr = *(const s8v*)(Kl + ((size_t)(ks * 4 + quad) * 64 + nb * 16 + ln) * 8);
#pragma unroll
                for (int mb = 0; mb < 2; ++mb)
                    s[mb][nb] = __builtin_amdgcn_mfma_f32_16x16x32_bf16(qf[mb][ks], kfr, s[mb][nb], 0, 0, 0);
            }

        bool edge = (kt == ktmax_w);   // mask needed only on the diagonal tile
#pragma unroll
        for (int mb = 0; mb < 2; ++mb) {
#pragma unroll
            for (int r = 0; r < 4; ++r) {
                int rloc = mb * 16 + quad * 4 + r;
                float p[4];
                if (!edge) {
#pragma unroll
                    for (int nb = 0; nb < 4; ++nb)
                        p[nb] = fast_exp2(s[mb][nb][r]);
                } else {
                    int grow = qt * 128 + wrow0 + rloc;
#pragma unroll
                    for (int nb = 0; nb < 4; ++nb) {
                        int key = kt * 64 + nb * 16 + ln;
                        float e = fast_exp2(s[mb][nb][r]);
                        p[nb] = (key > grow) ? 0.f : e;
                    }
                }
                l_part[mb][r] += (p[0] + p[1]) + (p[2] + p[3]);
#pragma unroll
                for (int nb = 0; nb < 4; ++nb)
                    Pw[rloc * 72 + nb * 16 + ln] = f2bf(p[nb]);
            }
        }

#pragma unroll
        for (int ks = 0; ks < 2; ++ks) {
            s8v pf_[2];
#pragma unroll
            for (int mb = 0; mb < 2; ++mb)
                pf_[mb] = *(const s8v*)(Pw + (mb * 16 + ln) * 72 + ks * 32 + quad * 8);
#pragma unroll
            for (int db = 0; db < 4; ++db) {
                s8v vfr = *(const s8v*)(Vl + ((size_t)(ks * 4 + quad) * 64 + db * 16 + ln) * 8);
#pragma unroll
                for (int mb = 0; mb < 2; ++mb)
                    o[mb][db] = __builtin_amdgcn_mfma_f32_16x16x32_bf16(pf_[mb], vfr, o[mb][db], 0, 0, 0);
            }
        }
    }

    // drain outstanding GLDS before epilogue/exit (skipping waves have loads in flight)
    asm volatile("s_waitcnt vmcnt(0)" ::: "memory");

#pragma unroll
    for (int mb = 0; mb < 2; ++mb)
#pragma unroll
        for (int r = 0; r < 4; ++r) {
            float l = l_part[mb][r];
#pragma unroll
            for (int msk = 1; msk < 16; msk <<= 1)
                l += __shfl_xor(l, msk);
            float inv = 1.0f / l;
            size_t row = qrow0 + wrow0 + mb * 16 + quad * 4 + r;
#pragma unroll
            for (int db = 0; db < 4; ++db)
                ctx[row * EMB + h * 64 + db * 16 + ln] = f2bf(o[mb][db][r] * inv);
        }
}

extern "C" void kernel_launch(void* const* d_in, const int* in_sizes, int n_in,
                              void* d_out, int out_size, void* d_ws, size_t ws_size,
                              hipStream_t stream) {
    const float* x    = (const float*)d_in[0];
    const float* Wq   = (const float*)d_in[1];
    const float* Wk   = (const float*)d_in[2];
    const float* Wv   = (const float*)d_in[3];
    const float* Wo   = (const float*)d_in[4];
    const float* bo   = (const float*)d_in[5];
    const float* W1   = (const float*)d_in[6];
    const float* b1   = (const float*)d_in[7];
    const float* W2   = (const float*)d_in[8];
    const float* b2   = (const float*)d_in[9];
    const float* ln1s = (const float*)d_in[10];
    const float* ln1b = (const float*)d_in[11];
    const float* ln2s = (const float*)d_in[12];
    const float* ln2b = (const float*)d_in[13];
    float* out = (float*)d_out;

    const size_t MiB = 1024 * 1024;
    uint8_t* w8 = (uint8_t*)d_ws;
    unsigned short* Wqkv_t = (unsigned short*)(w8);             //  0..6   [3072][1024]
    unsigned short* Wo_t   = (unsigned short*)(w8 +  6 * MiB);  //  6..8   [1024][1024]
    unsigned short* W1_t   = (unsigned short*)(w8 +  8 * MiB);  //  8..16  [4096][1024]
    unsigned short* W2_t   = (unsigned short*)(w8 + 16 * MiB);  // 16..24  [1024][4096]
    unsigned short* act_bf = (unsigned short*)(w8 + 24 * MiB);  // 24..32  h1/ctx/h2
    unsigned short* qk_bf  = (unsigned short*)(w8 + 32 * MiB);  // 32..48  [4096][2048]
    unsigned short* vt     = (unsigned short*)(w8 + 48 * MiB);  // 48..56  [2048][2048]
    float*          p0a    = (float*)(w8 + 32 * MiB);           // 32..48  (after attn)
    float*          p1a    = (float*)(w8 + 48 * MiB);           // 48..64
    unsigned short* u_bf   = (unsigned short*)(w8 + 32 * MiB);  // 32..64  (step 6+)
    float*          x1     = (float*)(w8 + 64 * MiB);           // 64..80
    float*          p0b    = (float*)(w8);                      //  0..16  (weights dead)
    float*          p1b    = (float*)(w8 + 80 * MiB);           // 80..96

    // 0) all weight converts in one dispatch
    tconv_all_kernel<<<3072, 256, 0, stream>>>(Wq, Wk, Wv, Wo, W1, W2,
                                               Wqkv_t, Wo_t, W1_t, W2_t);

    // 1) LN1 -> bf16
    ln_bf16_kernel<<<NTOK, 256, 0, stream>>>(x, ln1s, ln1b, act_bf);

    // 2) fused QKV (8-phase 256x256; q prescaled, q/k row-major bf16, v -> vt)
    gemm_8ph_kernel<<<(NTOK / 256) * (QKV_N / 256), 512, 0, stream>>>(
        act_bf, Wqkv_t, qk_bf, NTOK, QKV_N, EMB, nullptr, 0, 1, vt);

    // 3) double-buffered MFMA flash attention -> ctx bf16
    flash_attn_mfma_kernel<<<dim3(HEADS, SEQ / 128, BATCH), 256, 0, stream>>>(qk_bf, vt, act_bf);

    // 4+5) x1 = x + ctx @ Wo + bo (split-K2); fused reduce+LN2
    gemm_bf16_kernel<<<dim3(EMB / 128, NTOK / 128, 2), 256, 0, stream>>>(
        act_bf, Wo_t, p0a, p1a, NTOK, EMB, EMB, 512);
    reduce_ln_kernel<<<NTOK, 256, 0, stream>>>(p0a, p1a, bo, x, x1, ln2s, ln2b, act_bf);

    // 6) u = gelu(h2 @ W1 + b1) -> bf16  (8-phase 256x256)
    gemm_8ph_kernel<<<(NTOK / 256) * (FF_DIM / 256), 512, 0, stream>>>(
        act_bf, W1_t, u_bf, NTOK, FF_DIM, EMB, b1, 1, 0, nullptr);

    // 7) out = x1 + u @ W2 + b2   (split-K2)
    gemm_bf16_kernel<<<dim3(EMB / 128, NTOK / 128, 2), 256, 0, stream>>>(
        u_bf, W2_t, p0b, p1b, NTOK, EMB, FF_DIM, 2048);
    reduce_kernel<<<(NTOK * EMB) / 1024, 256, 0, stream>>>(p0b, p1b, b2, x1, out);
}